// Round 1
// baseline (1541.254 us; speedup 1.0000x reference)
//
#include <hip/hip_runtime.h>

#define NN 20000
#define NE 320000
#define DD 512

__device__ __forceinline__ float sigmoidf_(float x) { return 1.f / (1.f + expf(-x)); }

// ---------------- degree / norm ----------------
__global__ void k_init(float* deg, int* cnt) {
  int i = blockIdx.x * 256 + threadIdx.x;
  if (i < NN) { deg[i] = 1.0f; cnt[i] = 0; }   // self-loop weight 1 pre-added
}

__global__ void k_accum(const int* col, const float* w, float* deg, int* cnt) {
  int e = blockIdx.x * 256 + threadIdx.x;
  if (e < NE) {
    int c = col[e];
    atomicAdd(&deg[c], w[e]);
    atomicAdd(&cnt[c], 1);
  }
}

__global__ void k_dinv(const float* deg, float* dinv) {
  int i = blockIdx.x * 256 + threadIdx.x;
  if (i < NN) dinv[i] = rsqrtf(deg[i]);   // deg >= 1 always (self loop)
}

// single-block exclusive scan over cnt[NN] -> ptr[NN+1], copy to pos
__global__ void k_scan(const int* cnt, int* ptr, int* pos) {
  __shared__ int sdata[1024];
  const int ITEMS = (NN + 1023) / 1024;  // 20
  int tid = threadIdx.x;
  int base = tid * ITEMS;
  int s = 0;
  for (int j = 0; j < ITEMS; ++j) { int i = base + j; if (i < NN) s += cnt[i]; }
  sdata[tid] = s;
  __syncthreads();
  for (int off = 1; off < 1024; off <<= 1) {
    int v = 0;
    if (tid >= off) v = sdata[tid - off];
    __syncthreads();
    sdata[tid] += v;
    __syncthreads();
  }
  int run = (tid == 0) ? 0 : sdata[tid - 1];
  for (int j = 0; j < ITEMS; ++j) {
    int i = base + j;
    if (i < NN) { ptr[i] = run; pos[i] = run; run += cnt[i]; }
  }
  if (tid == 0) ptr[NN] = NE;
}

__global__ void k_scatter(const int* row, const int* col, const float* w, const float* dinv,
                          int* pos, int* erow, float* enorm) {
  int e = blockIdx.x * 256 + threadIdx.x;
  if (e < NE) {
    int r = row[e], c = col[e];
    int slot = atomicAdd(&pos[c], 1);
    erow[slot] = r;
    enorm[slot] = dinv[r] * w[e] * dinv[c];
  }
}

// ---------------- f32 tiled GEMM: C = A1@W1 (+ A2@W2), K=N=512 ----------------
__global__ __launch_bounds__(256) void k_gemm_dual(const float* A1, const float* W1,
                                                   const float* A2, const float* W2,
                                                   float* C, int M) {
  __shared__ __align__(16) float As[16][68];
  __shared__ __align__(16) float Ws[16][68];
  int tid = threadIdx.x;
  int tx = tid & 15, ty = tid >> 4;
  int rowBase = blockIdx.y * 64;
  int colBase = blockIdx.x * 64;
  float acc[4][4] = {};

  for (int pass = 0; pass < 2; ++pass) {
    const float* A = pass ? A2 : A1;
    const float* W = pass ? W2 : W1;
    if (!A) break;
    for (int k0 = 0; k0 < 512; k0 += 16) {
#pragma unroll
      for (int i = 0; i < 4; ++i) {
        int idx = tid + i * 256;
        int r = idx >> 4, kk = idx & 15;
        int grow = rowBase + r;
        As[kk][r] = (grow < M) ? A[(size_t)grow * 512 + k0 + kk] : 0.f;
      }
#pragma unroll
      for (int i = 0; i < 4; ++i) {
        int idx = tid + i * 256;
        int kk = idx >> 6, n = idx & 63;
        Ws[kk][n] = W[(size_t)(k0 + kk) * 512 + colBase + n];
      }
      __syncthreads();
#pragma unroll
      for (int kk = 0; kk < 16; ++kk) {
        float4 av = *(const float4*)&As[kk][ty * 4];
        float4 bv = *(const float4*)&Ws[kk][tx * 4];
        acc[0][0] += av.x * bv.x; acc[0][1] += av.x * bv.y; acc[0][2] += av.x * bv.z; acc[0][3] += av.x * bv.w;
        acc[1][0] += av.y * bv.x; acc[1][1] += av.y * bv.y; acc[1][2] += av.y * bv.z; acc[1][3] += av.y * bv.w;
        acc[2][0] += av.z * bv.x; acc[2][1] += av.z * bv.y; acc[2][2] += av.z * bv.z; acc[2][3] += av.z * bv.w;
        acc[3][0] += av.w * bv.x; acc[3][1] += av.w * bv.y; acc[3][2] += av.w * bv.z; acc[3][3] += av.w * bv.w;
      }
      __syncthreads();
    }
  }
#pragma unroll
  for (int i = 0; i < 4; ++i) {
    int grow = rowBase + ty * 4 + i;
    if (grow < M) {
      float4 v = make_float4(acc[i][0], acc[i][1], acc[i][2], acc[i][3]);
      *(float4*)(C + (size_t)grow * 512 + colBase + tx * 4) = v;
    }
  }
}

// ---------------- aggregation: dest = f(Agg(M) + b1 + b2), one block per node ----------------
__global__ __launch_bounds__(256) void k_agg_sig(const float* __restrict__ M,
                                                 const int* __restrict__ ptr,
                                                 const int* __restrict__ erow,
                                                 const float* __restrict__ enorm,
                                                 const float* __restrict__ dinv,
                                                 const float* __restrict__ b1,
                                                 const float* __restrict__ b2,
                                                 const float* __restrict__ Hmul,  // nullable
                                                 float* __restrict__ dest) {
  int i = blockIdx.x;
  int c = threadIdx.x * 2;
  float s = dinv[i];
  float s2 = s * s;
  float2 m0 = *(const float2*)(M + (size_t)i * DD + c);
  float accx = s2 * m0.x, accy = s2 * m0.y;
  int e1 = ptr[i + 1];
  for (int e = ptr[i]; e < e1; ++e) {
    int r = erow[e];
    float nm = enorm[e];
    float2 mv = *(const float2*)(M + (size_t)r * DD + c);
    accx += nm * mv.x;
    accy += nm * mv.y;
  }
  float vx = sigmoidf_(accx + b1[c] + b2[c]);
  float vy = sigmoidf_(accy + b1[c + 1] + b2[c + 1]);
  if (Hmul) {
    vx *= Hmul[(size_t)i * DD + c];
    vy *= Hmul[(size_t)i * DD + c + 1];
  }
  *(float2*)(dest + (size_t)i * DD + c) = make_float2(vx, vy);
}

// fused: out = Z*H + (1-Z)*tanh(Agg(Mx)+bx + Agg(Mh)+bh)   (Z aliases out, elementwise)
__global__ __launch_bounds__(256) void k_agg_final(const float* __restrict__ Mx,
                                                   const float* __restrict__ Mh,
                                                   const int* __restrict__ ptr,
                                                   const int* __restrict__ erow,
                                                   const float* __restrict__ enorm,
                                                   const float* __restrict__ dinv,
                                                   const float* __restrict__ bx,
                                                   const float* __restrict__ bh,
                                                   const float* __restrict__ Z,
                                                   const float* __restrict__ H,
                                                   float* __restrict__ out) {
  int i = blockIdx.x;
  int c = threadIdx.x * 2;
  float s = dinv[i];
  float s2 = s * s;
  float2 x0 = *(const float2*)(Mx + (size_t)i * DD + c);
  float2 h0 = *(const float2*)(Mh + (size_t)i * DD + c);
  float ax = s2 * x0.x, ay = s2 * x0.y;
  float bx_ = s2 * h0.x, by_ = s2 * h0.y;
  int e1 = ptr[i + 1];
  for (int e = ptr[i]; e < e1; ++e) {
    int r = erow[e];
    float nm = enorm[e];
    float2 xv = *(const float2*)(Mx + (size_t)r * DD + c);
    float2 hv = *(const float2*)(Mh + (size_t)r * DD + c);
    ax += nm * xv.x; ay += nm * xv.y;
    bx_ += nm * hv.x; by_ += nm * hv.y;
  }
  float tx_ = tanhf(ax + bx[c] + bx_ + bh[c]);
  float ty_ = tanhf(ay + bx[c + 1] + by_ + bh[c + 1]);
  float zx = Z[(size_t)i * DD + c], zy = Z[(size_t)i * DD + c + 1];
  float hx = H[(size_t)i * DD + c], hy = H[(size_t)i * DD + c + 1];
  float2 o;
  o.x = zx * hx + (1.f - zx) * tx_;
  o.y = zy * hy + (1.f - zy) * ty_;
  *(float2*)(out + (size_t)i * DD + c) = o;
}

extern "C" void kernel_launch(void* const* d_in, const int* in_sizes, int n_in,
                              void* d_out, int out_size, void* d_ws, size_t ws_size,
                              hipStream_t stream) {
  const float* X   = (const float*)d_in[0];
  const int*   ei  = (const int*)d_in[1];
  const float* ew  = (const float*)d_in[2];
  const float* H   = (const float*)d_in[3];
  const float* Wxz = (const float*)d_in[4];  const float* bxz = (const float*)d_in[5];
  const float* Whz = (const float*)d_in[6];  const float* bhz = (const float*)d_in[7];
  const float* Wxr = (const float*)d_in[8];  const float* bxr = (const float*)d_in[9];
  const float* Whr = (const float*)d_in[10]; const float* bhr = (const float*)d_in[11];
  const float* Wxh = (const float*)d_in[12]; const float* bxh = (const float*)d_in[13];
  const float* Whh = (const float*)d_in[14]; const float* bhh = (const float*)d_in[15];
  const int* row = ei;
  const int* col = ei + NE;
  float* out = (float*)d_out;

  char* base = (char*)d_ws;
  size_t o = 0;
  auto alloc = [&](size_t b) { char* p = base + o; o += (b + 255) & ~(size_t)255; return p; };
  float* B0   = (float*)alloc((size_t)NN * DD * 4);
  float* B1   = (float*)alloc((size_t)NN * DD * 4);
  float* B2   = (float*)alloc((size_t)NN * DD * 4);
  float* deg  = (float*)alloc(NN * 4);
  float* dinv = (float*)alloc(NN * 4);
  int*   cnt  = (int*)alloc(NN * 4);
  int*   ptr  = (int*)alloc((NN + 1) * 4);
  int*   pos  = (int*)alloc(NN * 4);
  int*   erow = (int*)alloc(NE * 4);
  float* enorm= (float*)alloc(NE * 4);

  dim3 b256(256);
  int gN = (NN + 255) / 256;
  int gE = (NE + 255) / 256;

  // graph normalization + CSR build
  k_init<<<gN, b256, 0, stream>>>(deg, cnt);
  k_accum<<<gE, b256, 0, stream>>>(col, ew, deg, cnt);
  k_dinv<<<gN, b256, 0, stream>>>(deg, dinv);
  k_scan<<<1, 1024, 0, stream>>>(cnt, ptr, pos);
  k_scatter<<<gE, b256, 0, stream>>>(row, col, ew, dinv, pos, erow, enorm);

  // phase-1 GEMMs: M_z = X@Wxz + H@Whz ; M_r = X@Wxr + H@Whr ; M_x = X@Wxh
  dim3 gemmGrid(512 / 64, (NN + 63) / 64);
  k_gemm_dual<<<gemmGrid, b256, 0, stream>>>(X, Wxz, H, Whz, B0, NN);
  k_gemm_dual<<<gemmGrid, b256, 0, stream>>>(X, Wxr, H, Whr, B1, NN);
  k_gemm_dual<<<gemmGrid, b256, 0, stream>>>(X, Wxh, nullptr, nullptr, B2, NN);

  // Z = sigmoid(Agg(M_z)+b)  -> d_out ;  HR = H * sigmoid(Agg(M_r)+b) -> B0
  k_agg_sig<<<NN, b256, 0, stream>>>(B0, ptr, erow, enorm, dinv, bxz, bhz, nullptr, out);
  k_agg_sig<<<NN, b256, 0, stream>>>(B1, ptr, erow, enorm, dinv, bxr, bhr, H, B0);

  // M_h = HR @ Whh -> B1
  k_gemm_dual<<<gemmGrid, b256, 0, stream>>>(B0, Whh, nullptr, nullptr, B1, NN);

  // out = Z*H + (1-Z)*tanh(Agg(M_x)+bxh + Agg(M_h)+bhh)
  k_agg_final<<<NN, b256, 0, stream>>>(B2, B1, ptr, erow, enorm, dinv, bxh, bhh, out, H, out);
}

// Round 2
// 653.515 us; speedup vs baseline: 2.3584x; 2.3584x over previous
//
#include <hip/hip_runtime.h>

#define NN 20000
#define NP 20096   // padded rows (multiple of 128)
#define NE 320000
#define DD 512

typedef __bf16 bf16x8 __attribute__((ext_vector_type(8)));
typedef float f32x4 __attribute__((ext_vector_type(4)));

__device__ __forceinline__ float sigmoidf_(float x) { return 1.f / (1.f + expf(-x)); }

__device__ __forceinline__ unsigned bf16pair(float a, float b) {
  unsigned ua = __builtin_bit_cast(unsigned, a);
  unsigned ub = __builtin_bit_cast(unsigned, b);
  ua = (ua + 0x7FFFu + ((ua >> 16) & 1u)) >> 16;
  ub = (ub + 0x7FFFu + ((ub >> 16) & 1u)) >> 16;
  return ua | (ub << 16);
}
__device__ __forceinline__ unsigned short bf16one(float a) {
  unsigned ua = __builtin_bit_cast(unsigned, a);
  return (unsigned short)((ua + 0x7FFFu + ((ua >> 16) & 1u)) >> 16);
}

__device__ __forceinline__ void gload16(const void* g, void* l) {
  __builtin_amdgcn_global_load_lds(
      (const __attribute__((address_space(1))) unsigned int*)g,
      (__attribute__((address_space(3))) unsigned int*)l, 16, 0, 0);
}

// ---------------- degree / norm / CSR ----------------
__global__ void k_init(float* deg, int* cnt) {
  int i = blockIdx.x * 256 + threadIdx.x;
  if (i < NN) { deg[i] = 1.0f; cnt[i] = 0; }
}

__global__ void k_accum(const int* col, const float* w, float* deg, int* cnt) {
  int e = blockIdx.x * 256 + threadIdx.x;
  if (e < NE) {
    int c = col[e];
    atomicAdd(&deg[c], w[e]);
    atomicAdd(&cnt[c], 1);
  }
}

__global__ void k_dinv(const float* deg, float* dinv) {
  int i = blockIdx.x * 256 + threadIdx.x;
  if (i < NN) dinv[i] = rsqrtf(deg[i]);
}

__global__ void k_scan(const int* cnt, int* ptr, int* pos) {
  __shared__ int sdata[1024];
  const int ITEMS = (NN + 1023) / 1024;
  int tid = threadIdx.x;
  int base = tid * ITEMS;
  int s = 0;
  for (int j = 0; j < ITEMS; ++j) { int i = base + j; if (i < NN) s += cnt[i]; }
  sdata[tid] = s;
  __syncthreads();
  for (int off = 1; off < 1024; off <<= 1) {
    int v = 0;
    if (tid >= off) v = sdata[tid - off];
    __syncthreads();
    sdata[tid] += v;
    __syncthreads();
  }
  int run = (tid == 0) ? 0 : sdata[tid - 1];
  for (int j = 0; j < ITEMS; ++j) {
    int i = base + j;
    if (i < NN) { ptr[i] = run; pos[i] = run; run += cnt[i]; }
  }
  if (tid == 0) ptr[NN] = NE;
}

__global__ void k_scatter(const int* row, const int* col, const float* w, const float* dinv,
                          int* pos, int* erow, float* enorm) {
  int e = blockIdx.x * 256 + threadIdx.x;
  if (e < NE) {
    int r = row[e], c = col[e];
    int slot = atomicAdd(&pos[c], 1);
    erow[slot] = r;
    enorm[slot] = dinv[r] * w[e] * dinv[c];
  }
}

// ---------------- conversions ----------------
// f32 -> bf16, 8 elems/thread
__global__ void k_cvt_bf16(const float* __restrict__ src, unsigned short* __restrict__ dst, int n8) {
  int i = blockIdx.x * 256 + threadIdx.x;
  if (i >= n8) return;
  const float4* s = (const float4*)src;
  float4 v0 = s[i * 2], v1 = s[i * 2 + 1];
  uint4 o;
  o.x = bf16pair(v0.x, v0.y);
  o.y = bf16pair(v0.z, v0.w);
  o.z = bf16pair(v1.x, v1.y);
  o.w = bf16pair(v1.z, v1.w);
  ((uint4*)dst)[i] = o;
}

// W [512][512] f32 -> Wt [n][k] bf16 (transposed)
__global__ void k_wt(const float* __restrict__ W, unsigned short* __restrict__ Wt) {
  __shared__ float t[32][33];
  int tx = threadIdx.x, ty = threadIdx.y;  // (32,8)
  int kb = blockIdx.x * 32, nb = blockIdx.y * 32;
#pragma unroll
  for (int i = 0; i < 4; ++i)
    t[ty * 4 + i][tx] = W[(size_t)(kb + ty * 4 + i) * 512 + nb + tx];
  __syncthreads();
#pragma unroll
  for (int i = 0; i < 4; ++i)
    Wt[(size_t)(nb + ty * 4 + i) * 512 + kb + tx] = bf16one(t[tx][ty * 4 + i]);
}

// ---------------- MFMA GEMM: C[f32] = A1@W1t^T (+ A2@W2t^T) ----------------
// A: [NP][512] bf16 row-major. Wt: [512][512] bf16, Wt[n][k] = W[k][n].
// 128x128 tile, BK=64, 4 waves (2x2), 4x4 16x16x32 frags per wave.
// LDS XOR-swizzle (row&7)<<4 on the 128B rows; staged via global_load_lds
// with inverse-swizzled per-lane global source (rule 21).
__global__ __launch_bounds__(256) void k_gemm_mfma(
    const unsigned short* __restrict__ A1, const unsigned short* __restrict__ W1t,
    const unsigned short* __restrict__ A2, const unsigned short* __restrict__ W2t,
    float* __restrict__ C) {
  __shared__ unsigned char smem[32768];  // As 16KB | Bs 16KB
  const int tid = threadIdx.x;
  const int lane = tid & 63, w = tid >> 6;
  const int wr = w >> 1, wc = w & 1;
  const int rowBase = blockIdx.y * 128;
  const int colBase = blockIdx.x * 128;

  f32x4 acc[4][4] = {};

  const int lrow = lane & 15;
  const int lkb = (lane >> 4) << 4;          // 0,16,32,48 (bytes)
  const int swz = (lane & 7) << 4;           // read-side swizzle (row&7)<<4 == (lane&7)<<4
  const int srow = w * 32 + (lane >> 3);     // staging row (+ t*8)
  const int scol = (((lane & 7) ^ (lane >> 3)) << 4);  // pre-swizzled source byte col

  for (int pass = 0; pass < 2; ++pass) {
    const unsigned short* A = pass ? A2 : A1;
    const unsigned short* Wt = pass ? W2t : W1t;
    if (!A) break;
    const char* Abase = (const char*)A + (size_t)(rowBase + srow) * 1024 + scol;
    const char* Bbase = (const char*)Wt + (size_t)(colBase + srow) * 1024 + scol;
    for (int k0 = 0; k0 < 512; k0 += 64) {
      __syncthreads();
#pragma unroll
      for (int t = 0; t < 4; ++t) {
        gload16(Abase + (size_t)t * 8192 + k0 * 2, &smem[w * 4096 + t * 1024]);
        gload16(Bbase + (size_t)t * 8192 + k0 * 2, &smem[16384 + w * 4096 + t * 1024]);
      }
      __syncthreads();
#pragma unroll
      for (int ks = 0; ks < 2; ++ks) {
        bf16x8 af[4], bfr[4];
#pragma unroll
        for (int fm = 0; fm < 4; ++fm) {
          int row = wr * 64 + fm * 16 + lrow;
          int byte = row * 128 + (((ks << 6) + lkb) ^ swz);
          af[fm] = *(const bf16x8*)&smem[byte];
        }
#pragma unroll
        for (int fn = 0; fn < 4; ++fn) {
          int row = wc * 64 + fn * 16 + lrow;
          int byte = 16384 + row * 128 + (((ks << 6) + lkb) ^ swz);
          bfr[fn] = *(const bf16x8*)&smem[byte];
        }
#pragma unroll
        for (int fm = 0; fm < 4; ++fm)
#pragma unroll
          for (int fn = 0; fn < 4; ++fn)
            acc[fm][fn] = __builtin_amdgcn_mfma_f32_16x16x32_bf16(af[fm], bfr[fn], acc[fm][fn], 0, 0, 0);
      }
    }
  }
  // epilogue: C/D layout col=lane&15, row=(lane>>4)*4+reg
#pragma unroll
  for (int fm = 0; fm < 4; ++fm) {
    int rbase = rowBase + wr * 64 + fm * 16 + ((lane >> 4) << 2);
#pragma unroll
    for (int fn = 0; fn < 4; ++fn) {
      int col = colBase + wc * 64 + fn * 16 + lrow;
#pragma unroll
      for (int r = 0; r < 4; ++r)
        C[(size_t)(rbase + r) * 512 + col] = acc[fm][fn][r];
    }
  }
}

// ---------------- aggregation: dest = sigmoid(Agg(M)+b1+b2), f32 out ----------------
__global__ __launch_bounds__(256) void k_agg_sig(const float* __restrict__ M,
                                                 const int* __restrict__ ptr,
                                                 const int* __restrict__ erow,
                                                 const float* __restrict__ enorm,
                                                 const float* __restrict__ dinv,
                                                 const float* __restrict__ b1,
                                                 const float* __restrict__ b2,
                                                 float* __restrict__ dest) {
  int i = blockIdx.x;
  int c = threadIdx.x * 2;
  float s = dinv[i];
  float s2 = s * s;
  float2 m0 = *(const float2*)(M + (size_t)i * DD + c);
  float accx = s2 * m0.x, accy = s2 * m0.y;
  int e1 = ptr[i + 1];
  for (int e = ptr[i]; e < e1; ++e) {
    int r = erow[e];
    float nm = enorm[e];
    float2 mv = *(const float2*)(M + (size_t)r * DD + c);
    accx += nm * mv.x;
    accy += nm * mv.y;
  }
  float vx = sigmoidf_(accx + b1[c] + b2[c]);
  float vy = sigmoidf_(accy + b1[c + 1] + b2[c + 1]);
  *(float2*)(dest + (size_t)i * DD + c) = make_float2(vx, vy);
}

// HR = H * sigmoid(Agg(M)+b1+b2) -> bf16
__global__ __launch_bounds__(256) void k_agg_sig_hr(const float* __restrict__ M,
                                                    const int* __restrict__ ptr,
                                                    const int* __restrict__ erow,
                                                    const float* __restrict__ enorm,
                                                    const float* __restrict__ dinv,
                                                    const float* __restrict__ b1,
                                                    const float* __restrict__ b2,
                                                    const float* __restrict__ H,
                                                    unsigned short* __restrict__ dest) {
  int i = blockIdx.x;
  int c = threadIdx.x * 2;
  float s = dinv[i];
  float s2 = s * s;
  float2 m0 = *(const float2*)(M + (size_t)i * DD + c);
  float accx = s2 * m0.x, accy = s2 * m0.y;
  int e1 = ptr[i + 1];
  for (int e = ptr[i]; e < e1; ++e) {
    int r = erow[e];
    float nm = enorm[e];
    float2 mv = *(const float2*)(M + (size_t)r * DD + c);
    accx += nm * mv.x;
    accy += nm * mv.y;
  }
  float vx = sigmoidf_(accx + b1[c] + b2[c]) * H[(size_t)i * DD + c];
  float vy = sigmoidf_(accy + b1[c + 1] + b2[c + 1]) * H[(size_t)i * DD + c + 1];
  *(unsigned*)(dest + (size_t)i * DD + c) = bf16pair(vx, vy);
}

// out = Z*H + (1-Z)*tanh(Agg(Mx)+bx + Agg(Mh)+bh)   (Z aliases out)
__global__ __launch_bounds__(256) void k_agg_final(const float* __restrict__ Mx,
                                                   const float* __restrict__ Mh,
                                                   const int* __restrict__ ptr,
                                                   const int* __restrict__ erow,
                                                   const float* __restrict__ enorm,
                                                   const float* __restrict__ dinv,
                                                   const float* __restrict__ bx,
                                                   const float* __restrict__ bh,
                                                   const float* __restrict__ Z,
                                                   const float* __restrict__ H,
                                                   float* __restrict__ out) {
  int i = blockIdx.x;
  int c = threadIdx.x * 2;
  float s = dinv[i];
  float s2 = s * s;
  float2 x0 = *(const float2*)(Mx + (size_t)i * DD + c);
  float2 h0 = *(const float2*)(Mh + (size_t)i * DD + c);
  float ax = s2 * x0.x, ay = s2 * x0.y;
  float bx_ = s2 * h0.x, by_ = s2 * h0.y;
  int e1 = ptr[i + 1];
  for (int e = ptr[i]; e < e1; ++e) {
    int r = erow[e];
    float nm = enorm[e];
    float2 xv = *(const float2*)(Mx + (size_t)r * DD + c);
    float2 hv = *(const float2*)(Mh + (size_t)r * DD + c);
    ax += nm * xv.x; ay += nm * xv.y;
    bx_ += nm * hv.x; by_ += nm * hv.y;
  }
  float tx_ = tanhf(ax + bx[c] + bx_ + bh[c]);
  float ty_ = tanhf(ay + bx[c + 1] + by_ + bh[c + 1]);
  float zx = Z[(size_t)i * DD + c], zy = Z[(size_t)i * DD + c + 1];
  float hx = H[(size_t)i * DD + c], hy = H[(size_t)i * DD + c + 1];
  float2 o;
  o.x = zx * hx + (1.f - zx) * tx_;
  o.y = zy * hy + (1.f - zy) * ty_;
  *(float2*)(out + (size_t)i * DD + c) = o;
}

extern "C" void kernel_launch(void* const* d_in, const int* in_sizes, int n_in,
                              void* d_out, int out_size, void* d_ws, size_t ws_size,
                              hipStream_t stream) {
  const float* X   = (const float*)d_in[0];
  const int*   ei  = (const int*)d_in[1];
  const float* ew  = (const float*)d_in[2];
  const float* H   = (const float*)d_in[3];
  const float* Wxz = (const float*)d_in[4];  const float* bxz = (const float*)d_in[5];
  const float* Whz = (const float*)d_in[6];  const float* bhz = (const float*)d_in[7];
  const float* Wxr = (const float*)d_in[8];  const float* bxr = (const float*)d_in[9];
  const float* Whr = (const float*)d_in[10]; const float* bhr = (const float*)d_in[11];
  const float* Wxh = (const float*)d_in[12]; const float* bxh = (const float*)d_in[13];
  const float* Whh = (const float*)d_in[14]; const float* bhh = (const float*)d_in[15];
  const int* row = ei;
  const int* col = ei + NE;
  float* out = (float*)d_out;

  char* base = (char*)d_ws;
  size_t o = 0;
  auto alloc = [&](size_t b) { char* p = base + o; o += (b + 255) & ~(size_t)255; return p; };
  unsigned short* Xb  = (unsigned short*)alloc((size_t)NP * DD * 2);
  unsigned short* Hb  = (unsigned short*)alloc((size_t)NP * DD * 2);  // doubles as HRb
  float* B0   = (float*)alloc((size_t)NP * DD * 4);
  float* B1   = (float*)alloc((size_t)NP * DD * 4);
  unsigned short* Wt[6];
  for (int i = 0; i < 6; ++i) Wt[i] = (unsigned short*)alloc((size_t)512 * 512 * 2);
  float* deg  = (float*)alloc(NN * 4);
  float* dinv = (float*)alloc(NN * 4);
  int*   cnt  = (int*)alloc(NN * 4);
  int*   ptr  = (int*)alloc((NN + 1) * 4);
  int*   pos  = (int*)alloc(NN * 4);
  int*   erow = (int*)alloc(NE * 4);
  float* enorm= (float*)alloc(NE * 4);

  dim3 b256(256);
  int gN = (NN + 255) / 256;
  int gE = (NE + 255) / 256;

  // graph normalization + CSR build
  k_init<<<gN, b256, 0, stream>>>(deg, cnt);
  k_accum<<<gE, b256, 0, stream>>>(col, ew, deg, cnt);
  k_dinv<<<gN, b256, 0, stream>>>(deg, dinv);
  k_scan<<<1, 1024, 0, stream>>>(cnt, ptr, pos);
  k_scatter<<<gE, b256, 0, stream>>>(row, col, ew, dinv, pos, erow, enorm);

  // conversions
  int n8 = NN * DD / 8;
  k_cvt_bf16<<<(n8 + 255) / 256, b256, 0, stream>>>(X, Xb, n8);
  k_cvt_bf16<<<(n8 + 255) / 256, b256, 0, stream>>>(H, Hb, n8);
  dim3 wtb(32, 8), wtg(16, 16);
  const float* Ws[6] = {Wxz, Whz, Wxr, Whr, Wxh, Whh};
  for (int i = 0; i < 6; ++i) k_wt<<<wtg, wtb, 0, stream>>>(Ws[i], Wt[i]);

  dim3 gemmGrid(512 / 128, NP / 128);

  // M_z = X@Wxz + H@Whz -> B0 ; Z = sigmoid(Agg(B0)+b) -> out
  k_gemm_mfma<<<gemmGrid, b256, 0, stream>>>(Xb, Wt[0], Hb, Wt[1], B0);
  k_agg_sig<<<NN, b256, 0, stream>>>(B0, ptr, erow, enorm, dinv, bxz, bhz, out);

  // M_r = X@Wxr + H@Whr -> B1 ; HR = H*sigmoid(Agg(B1)+b) -> Hb (bf16, aliases Hb)
  k_gemm_mfma<<<gemmGrid, b256, 0, stream>>>(Xb, Wt[2], Hb, Wt[3], B1);
  k_agg_sig_hr<<<NN, b256, 0, stream>>>(B1, ptr, erow, enorm, dinv, bxr, bhr, H, Hb);

  // M_x = X@Wxh -> B0 (overwrite) ; M_h = HR@Whh -> B1 (overwrite)
  k_gemm_mfma<<<gemmGrid, b256, 0, stream>>>(Xb, Wt[4], nullptr, nullptr, B0);
  k_gemm_mfma<<<gemmGrid, b256, 0, stream>>>(Hb, Wt[5], nullptr, nullptr, B1);

  // out = Z*H + (1-Z)*tanh(Agg(B0)+bxh + Agg(B1)+bhh)
  k_agg_final<<<NN, b256, 0, stream>>>(B0, B1, ptr, erow, enorm, dinv, bxh, bhh, out, H, out);
}

// Round 3
// 422.205 us; speedup vs baseline: 3.6505x; 1.5479x over previous
//
#include <hip/hip_runtime.h>

#define NN 20000
#define NP 20096   // padded rows (multiple of 128)
#define NE 320000
#define DD 512

typedef __bf16 bf16x8 __attribute__((ext_vector_type(8)));
typedef float f32x4 __attribute__((ext_vector_type(4)));
typedef unsigned short u16;

__device__ __forceinline__ float sigmoidf_(float x) { return 1.f / (1.f + expf(-x)); }

__device__ __forceinline__ unsigned bf16pair(float a, float b) {
  unsigned ua = __builtin_bit_cast(unsigned, a);
  unsigned ub = __builtin_bit_cast(unsigned, b);
  ua = (ua + 0x7FFFu + ((ua >> 16) & 1u)) >> 16;
  ub = (ub + 0x7FFFu + ((ub >> 16) & 1u)) >> 16;
  return ua | (ub << 16);
}
__device__ __forceinline__ u16 bf16one(float a) {
  unsigned ua = __builtin_bit_cast(unsigned, a);
  return (u16)((ua + 0x7FFFu + ((ua >> 16) & 1u)) >> 16);
}
__device__ __forceinline__ float bflo(unsigned w) { return __builtin_bit_cast(float, w << 16); }
__device__ __forceinline__ float bfhi(unsigned w) { return __builtin_bit_cast(float, w & 0xFFFF0000u); }

__device__ __forceinline__ void gload16(const void* g, void* l) {
  __builtin_amdgcn_global_load_lds(
      (const __attribute__((address_space(1))) unsigned int*)g,
      (__attribute__((address_space(3))) unsigned int*)l, 16, 0, 0);
}

// ---------------- degree / norm / CSR ----------------
__global__ void k_init(float* deg, int* cnt) {
  int i = blockIdx.x * 256 + threadIdx.x;
  if (i < NN) { deg[i] = 1.0f; cnt[i] = 0; }
}

__global__ void k_accum(const int* col, const float* w, float* deg, int* cnt) {
  int e = blockIdx.x * 256 + threadIdx.x;
  if (e < NE) {
    int c = col[e];
    atomicAdd(&deg[c], w[e]);
    atomicAdd(&cnt[c], 1);
  }
}

__global__ void k_dinv(const float* deg, float* dinv) {
  int i = blockIdx.x * 256 + threadIdx.x;
  if (i < NN) dinv[i] = rsqrtf(deg[i]);
}

__global__ void k_scan(const int* cnt, int* ptr, int* pos) {
  __shared__ int sdata[1024];
  const int ITEMS = (NN + 1023) / 1024;
  int tid = threadIdx.x;
  int base = tid * ITEMS;
  int s = 0;
  for (int j = 0; j < ITEMS; ++j) { int i = base + j; if (i < NN) s += cnt[i]; }
  sdata[tid] = s;
  __syncthreads();
  for (int off = 1; off < 1024; off <<= 1) {
    int v = 0;
    if (tid >= off) v = sdata[tid - off];
    __syncthreads();
    sdata[tid] += v;
    __syncthreads();
  }
  int run = (tid == 0) ? 0 : sdata[tid - 1];
  for (int j = 0; j < ITEMS; ++j) {
    int i = base + j;
    if (i < NN) { ptr[i] = run; pos[i] = run; run += cnt[i]; }
  }
  if (tid == 0) ptr[NN] = NE;
}

__global__ void k_scatter(const int* row, const int* col, const float* w, const float* dinv,
                          int* pos, int* erow, float* enorm) {
  int e = blockIdx.x * 256 + threadIdx.x;
  if (e < NE) {
    int r = row[e], c = col[e];
    int slot = atomicAdd(&pos[c], 1);
    erow[slot] = r;
    enorm[slot] = dinv[r] * w[e] * dinv[c];
  }
}

// ---------------- conversions ----------------
__global__ void k_cvt_bf16(const float* __restrict__ src, u16* __restrict__ dst, int n8) {
  int i = blockIdx.x * 256 + threadIdx.x;
  if (i >= n8) return;
  const float4* s = (const float4*)src;
  float4 v0 = s[i * 2], v1 = s[i * 2 + 1];
  uint4 o;
  o.x = bf16pair(v0.x, v0.y);
  o.y = bf16pair(v0.z, v0.w);
  o.z = bf16pair(v1.x, v1.y);
  o.w = bf16pair(v1.z, v1.w);
  ((uint4*)dst)[i] = o;
}

// W [512][512] f32 -> Wt [n][k] bf16 (transposed)
__global__ void k_wt(const float* __restrict__ W, u16* __restrict__ Wt) {
  __shared__ float t[32][33];
  int tx = threadIdx.x, ty = threadIdx.y;  // (32,8)
  int kb = blockIdx.x * 32, nb = blockIdx.y * 32;
#pragma unroll
  for (int i = 0; i < 4; ++i)
    t[ty * 4 + i][tx] = W[(size_t)(kb + ty * 4 + i) * 512 + nb + tx];
  __syncthreads();
#pragma unroll
  for (int i = 0; i < 4; ++i)
    Wt[(size_t)(nb + ty * 4 + i) * 512 + kb + tx] = bf16one(t[tx][ty * 4 + i]);
}

// ---------------- sparse aggregation (pre-GEMM, bf16 in/out) ----------------
// wave-per-node; lane covers 8 contiguous bf16 columns (16B).
__global__ __launch_bounds__(256) void k_agg_dual(const u16* __restrict__ Xb,
                                                  const u16* __restrict__ Hb,
                                                  const int* __restrict__ ptr,
                                                  const int* __restrict__ erow,
                                                  const float* __restrict__ enorm,
                                                  const float* __restrict__ dinv,
                                                  u16* __restrict__ AXb,
                                                  u16* __restrict__ AHb) {
  int node = blockIdx.x * 4 + (threadIdx.x >> 6);
  if (node >= NN) return;
  int lane = threadIdx.x & 63;
  const uint4* X4 = (const uint4*)Xb;
  const uint4* H4 = (const uint4*)Hb;
  float ax[8] = {}, ah[8] = {};
  auto accum = [&](float nm, uint4 xv, uint4 hv) {
    unsigned xw[4] = {xv.x, xv.y, xv.z, xv.w};
    unsigned hw[4] = {hv.x, hv.y, hv.z, hv.w};
#pragma unroll
    for (int j = 0; j < 4; ++j) {
      ax[2 * j]     += nm * bflo(xw[j]);
      ax[2 * j + 1] += nm * bfhi(xw[j]);
      ah[2 * j]     += nm * bflo(hw[j]);
      ah[2 * j + 1] += nm * bfhi(hw[j]);
    }
  };
  float s = dinv[node];
  accum(s * s, X4[(size_t)node * 64 + lane], H4[(size_t)node * 64 + lane]);
  int e = ptr[node], e1 = ptr[node + 1];
  for (; e + 2 <= e1; e += 2) {
    int r0 = erow[e], r1 = erow[e + 1];
    float n0 = enorm[e], n1 = enorm[e + 1];
    uint4 x0 = X4[(size_t)r0 * 64 + lane];
    uint4 h0 = H4[(size_t)r0 * 64 + lane];
    uint4 x1 = X4[(size_t)r1 * 64 + lane];
    uint4 h1 = H4[(size_t)r1 * 64 + lane];
    accum(n0, x0, h0);
    accum(n1, x1, h1);
  }
  if (e < e1) {
    int r0 = erow[e];
    accum(enorm[e], X4[(size_t)r0 * 64 + lane], H4[(size_t)r0 * 64 + lane]);
  }
  uint4 ox, oh;
  ox.x = bf16pair(ax[0], ax[1]); ox.y = bf16pair(ax[2], ax[3]);
  ox.z = bf16pair(ax[4], ax[5]); ox.w = bf16pair(ax[6], ax[7]);
  oh.x = bf16pair(ah[0], ah[1]); oh.y = bf16pair(ah[2], ah[3]);
  oh.z = bf16pair(ah[4], ah[5]); oh.w = bf16pair(ah[6], ah[7]);
  ((uint4*)AXb)[(size_t)node * 64 + lane] = ox;
  ((uint4*)AHb)[(size_t)node * 64 + lane] = oh;
}

__global__ __launch_bounds__(256) void k_agg_single(const u16* __restrict__ Sb,
                                                    const int* __restrict__ ptr,
                                                    const int* __restrict__ erow,
                                                    const float* __restrict__ enorm,
                                                    const float* __restrict__ dinv,
                                                    u16* __restrict__ Ab) {
  int node = blockIdx.x * 4 + (threadIdx.x >> 6);
  if (node >= NN) return;
  int lane = threadIdx.x & 63;
  const uint4* S4 = (const uint4*)Sb;
  float ax[8] = {};
  auto accum = [&](float nm, uint4 xv) {
    unsigned xw[4] = {xv.x, xv.y, xv.z, xv.w};
#pragma unroll
    for (int j = 0; j < 4; ++j) {
      ax[2 * j]     += nm * bflo(xw[j]);
      ax[2 * j + 1] += nm * bfhi(xw[j]);
    }
  };
  float s = dinv[node];
  accum(s * s, S4[(size_t)node * 64 + lane]);
  int e = ptr[node], e1 = ptr[node + 1];
  for (; e + 2 <= e1; e += 2) {
    int r0 = erow[e], r1 = erow[e + 1];
    float n0 = enorm[e], n1 = enorm[e + 1];
    uint4 x0 = S4[(size_t)r0 * 64 + lane];
    uint4 x1 = S4[(size_t)r1 * 64 + lane];
    accum(n0, x0);
    accum(n1, x1);
  }
  if (e < e1) accum(enorm[e], S4[(size_t)erow[e] * 64 + lane]);
  uint4 ox;
  ox.x = bf16pair(ax[0], ax[1]); ox.y = bf16pair(ax[2], ax[3]);
  ox.z = bf16pair(ax[4], ax[5]); ox.w = bf16pair(ax[6], ax[7]);
  ((uint4*)Ab)[(size_t)node * 64 + lane] = ox;
}

// ---------------- MFMA GEMM + fused epilogue ----------------
// EPI 0: outF = sigmoid(acc+b1+b2)                      (Z)
// EPI 1: outB = bf16(H * sigmoid(acc+b1+b2))            (HR, bf16)
// EPI 2: outF = Z*H + (1-Z)*tanh(acc+b1+b2)             (final)
template <int EPI>
__global__ __launch_bounds__(256) void k_gemm_mfma(
    const u16* __restrict__ A1, const u16* __restrict__ W1t,
    const u16* __restrict__ A2, const u16* __restrict__ W2t,
    const float* __restrict__ b1, const float* __restrict__ b2,
    const float* __restrict__ H, const float* __restrict__ Z,
    float* __restrict__ outF, u16* __restrict__ outB) {
  __shared__ unsigned char smem[32768];  // As 16KB | Bs 16KB
  const int tid = threadIdx.x;
  const int lane = tid & 63, w = tid >> 6;
  const int wr = w >> 1, wc = w & 1;
  const int rowBase = blockIdx.y * 128;
  const int colBase = blockIdx.x * 128;

  f32x4 acc[4][4] = {};

  const int lrow = lane & 15;
  const int lkb = (lane >> 4) << 4;
  const int swz = (lane & 7) << 4;
  const int srow = w * 32 + (lane >> 3);
  const int scol = (((lane & 7) ^ (lane >> 3)) << 4);

  for (int pass = 0; pass < 2; ++pass) {
    const u16* A = pass ? A2 : A1;
    const u16* Wt = pass ? W2t : W1t;
    const char* Abase = (const char*)A + (size_t)(rowBase + srow) * 1024 + scol;
    const char* Bbase = (const char*)Wt + (size_t)(colBase + srow) * 1024 + scol;
    for (int k0 = 0; k0 < 512; k0 += 64) {
      __syncthreads();
#pragma unroll
      for (int t = 0; t < 4; ++t) {
        gload16(Abase + (size_t)t * 8192 + k0 * 2, &smem[w * 4096 + t * 1024]);
        gload16(Bbase + (size_t)t * 8192 + k0 * 2, &smem[16384 + w * 4096 + t * 1024]);
      }
      __syncthreads();
#pragma unroll
      for (int ks = 0; ks < 2; ++ks) {
        bf16x8 af[4], bfr[4];
#pragma unroll
        for (int fm = 0; fm < 4; ++fm) {
          int row = wr * 64 + fm * 16 + lrow;
          int byte = row * 128 + (((ks << 6) + lkb) ^ swz);
          af[fm] = *(const bf16x8*)&smem[byte];
        }
#pragma unroll
        for (int fn = 0; fn < 4; ++fn) {
          int row = wc * 64 + fn * 16 + lrow;
          int byte = 16384 + row * 128 + (((ks << 6) + lkb) ^ swz);
          bfr[fn] = *(const bf16x8*)&smem[byte];
        }
#pragma unroll
        for (int fm = 0; fm < 4; ++fm)
#pragma unroll
          for (int fn = 0; fn < 4; ++fn)
            acc[fm][fn] = __builtin_amdgcn_mfma_f32_16x16x32_bf16(af[fm], bfr[fn], acc[fm][fn], 0, 0, 0);
      }
    }
  }
  // epilogue: col=lane&15, row=(lane>>4)*4+reg
#pragma unroll
  for (int fm = 0; fm < 4; ++fm) {
    int rbase = rowBase + wr * 64 + fm * 16 + ((lane >> 4) << 2);
#pragma unroll
    for (int fn = 0; fn < 4; ++fn) {
      int col = colBase + wc * 64 + fn * 16 + lrow;
      float bb = b1[col] + b2[col];
#pragma unroll
      for (int r = 0; r < 4; ++r) {
        int row = rbase + r;
        if (row >= NN) continue;
        size_t idx = (size_t)row * 512 + col;
        float a = acc[fm][fn][r] + bb;
        if (EPI == 0) {
          outF[idx] = sigmoidf_(a);
        } else if (EPI == 1) {
          outB[idx] = bf16one(H[idx] * sigmoidf_(a));
        } else {
          float t = tanhf(a);
          float z = Z[idx];
          outF[idx] = z * H[idx] + (1.f - z) * t;
        }
      }
    }
  }
}

extern "C" void kernel_launch(void* const* d_in, const int* in_sizes, int n_in,
                              void* d_out, int out_size, void* d_ws, size_t ws_size,
                              hipStream_t stream) {
  const float* X   = (const float*)d_in[0];
  const int*   ei  = (const int*)d_in[1];
  const float* ew  = (const float*)d_in[2];
  const float* H   = (const float*)d_in[3];
  const float* Wxz = (const float*)d_in[4];  const float* bxz = (const float*)d_in[5];
  const float* Whz = (const float*)d_in[6];  const float* bhz = (const float*)d_in[7];
  const float* Wxr = (const float*)d_in[8];  const float* bxr = (const float*)d_in[9];
  const float* Whr = (const float*)d_in[10]; const float* bhr = (const float*)d_in[11];
  const float* Wxh = (const float*)d_in[12]; const float* bxh = (const float*)d_in[13];
  const float* Whh = (const float*)d_in[14]; const float* bhh = (const float*)d_in[15];
  const int* row = ei;
  const int* col = ei + NE;
  float* out = (float*)d_out;

  char* base = (char*)d_ws;
  size_t o = 0;
  auto alloc = [&](size_t b) { char* p = base + o; o += (b + 255) & ~(size_t)255; return p; };
  u16* Xb   = (u16*)alloc((size_t)NN * DD * 2);
  u16* Hb   = (u16*)alloc((size_t)NN * DD * 2);
  u16* AXb  = (u16*)alloc((size_t)NP * DD * 2);
  u16* AHb  = (u16*)alloc((size_t)NP * DD * 2);
  u16* HRb  = (u16*)alloc((size_t)NP * DD * 2);
  u16* AHRb = (u16*)alloc((size_t)NP * DD * 2);
  u16* Wt[6];
  for (int i = 0; i < 6; ++i) Wt[i] = (u16*)alloc((size_t)512 * 512 * 2);
  float* deg  = (float*)alloc(NN * 4);
  float* dinv = (float*)alloc(NN * 4);
  int*   cnt  = (int*)alloc(NN * 4);
  int*   ptr  = (int*)alloc((NN + 1) * 4);
  int*   pos  = (int*)alloc(NN * 4);
  int*   erow = (int*)alloc(NE * 4);
  float* enorm= (float*)alloc(NE * 4);

  dim3 b256(256);
  int gN = (NN + 255) / 256;
  int gE = (NE + 255) / 256;

  // graph normalization + CSR build
  k_init<<<gN, b256, 0, stream>>>(deg, cnt);
  k_accum<<<gE, b256, 0, stream>>>(col, ew, deg, cnt);
  k_dinv<<<gN, b256, 0, stream>>>(deg, dinv);
  k_scan<<<1, 1024, 0, stream>>>(cnt, ptr, pos);
  k_scatter<<<gE, b256, 0, stream>>>(row, col, ew, dinv, pos, erow, enorm);

  // conversions
  int n8 = NN * DD / 8;
  k_cvt_bf16<<<(n8 + 255) / 256, b256, 0, stream>>>(X, Xb, n8);
  k_cvt_bf16<<<(n8 + 255) / 256, b256, 0, stream>>>(H, Hb, n8);
  dim3 wtb(32, 8), wtg(16, 16);
  const float* Ws[6] = {Wxz, Whz, Wxr, Whr, Wxh, Whh};
  for (int i = 0; i < 6; ++i) k_wt<<<wtg, wtb, 0, stream>>>(Ws[i], Wt[i]);

  // AX = Agg(X), AH = Agg(H) in one sweep
  int gAgg = (NN + 3) / 4;
  k_agg_dual<<<gAgg, b256, 0, stream>>>(Xb, Hb, ptr, erow, enorm, dinv, AXb, AHb);

  dim3 gemmGrid(512 / 128, NP / 128);

  // Z = sigmoid(AX@Wxz + AH@Whz + b) -> out
  k_gemm_mfma<0><<<gemmGrid, b256, 0, stream>>>(AXb, Wt[0], AHb, Wt[1], bxz, bhz,
                                                nullptr, nullptr, out, nullptr);
  // HR = H * sigmoid(AX@Wxr + AH@Whr + b) -> HRb (bf16)
  k_gemm_mfma<1><<<gemmGrid, b256, 0, stream>>>(AXb, Wt[2], AHb, Wt[3], bxr, bhr,
                                                H, nullptr, nullptr, HRb);
  // AHR = Agg(HR)
  k_agg_single<<<gAgg, b256, 0, stream>>>(HRb, ptr, erow, enorm, dinv, AHRb);

  // out = Z*H + (1-Z)*tanh(AX@Wxh + AHR@Whh + b)
  k_gemm_mfma<2><<<gemmGrid, b256, 0, stream>>>(AXb, Wt[4], AHRb, Wt[5], bxh, bhh,
                                                H, out, out, nullptr);
}